// Round 1
// 708.893 us; speedup vs baseline: 1.0665x; 1.0665x over previous
//
#include <hip/hip_runtime.h>
#include <cstdint>
#include <cstddef>

// SparseConv3d: 3 chained sparse 3-tap convs (C=64) + BatchNorm(train) + ReLU.
// R3: per-lane VGPR gather straight into MFMA A-fragments (no LDS staging,
// no global_load_lds): lane l's A-frag is 16B at row(l&15)*128 + (l>>4)*16.
// Register double-buffer one full tile ahead (compiler emits counted vmcnt),
// nbr indices prefetched two tiles ahead. Center tap is provably self
// (nbr[n][1]==n by construction) -> streamed coalesced, no idx, no zero-check.
// B-fragments live in lane-linear LDS (conflict-free ds_read_b128), freeing
// 96 VGPRs; LDS 49->34 KB, launch_bounds(256,4) -> 16 waves/CU.

typedef __attribute__((ext_vector_type(4))) float float4v;
typedef __attribute__((ext_vector_type(4))) unsigned int uint4v;
typedef __attribute__((ext_vector_type(8))) __bf16 bf16x8;
typedef __attribute__((ext_vector_type(8))) unsigned short ushort8;

__device__ __forceinline__ unsigned short f2bf_bits(float f) {
    unsigned int u = __builtin_bit_cast(unsigned int, f);
    u += 0x7fffu + ((u >> 16) & 1u);   // round-to-nearest-even (finite inputs)
    return (unsigned short)(u >> 16);
}
__device__ __forceinline__ float bf2f(unsigned short b) {
    unsigned int u = ((unsigned int)b) << 16;
    return __builtin_bit_cast(float, u);
}

// fp32 -> bf16 table conversion (memory-bound elementwise).
__global__ __launch_bounds__(256)
void cvt_kernel(const float* __restrict__ in, unsigned short* __restrict__ out,
                size_t n8)
{
    size_t i = (size_t)blockIdx.x * 256 + threadIdx.x;
    const size_t stride = (size_t)gridDim.x * 256;
    for (; i < n8; i += stride) {
        const float4v* p = reinterpret_cast<const float4v*>(in + i * 8);
        float4v f0 = p[0], f1 = p[1];
        ushort8 u;
#pragma unroll
        for (int j = 0; j < 4; ++j) {
            u[j]     = f2bf_bits(f0[j]);
            u[j + 4] = f2bf_bits(f1[j]);
        }
        *reinterpret_cast<uint4v*>(out + i * 8) = __builtin_bit_cast(uint4v, u);
    }
}

// Issue one tile's 6 A-fragment loads (taps 0/2 gathered, tap 1 = self rows).
__device__ __forceinline__ void issue_tile(
    uint4v (&A)[6], const char* __restrict__ abase,
    const char* __restrict__ zaddr, int i0, int i2,
    int t, int l15, int quad)
{
    const int qo = quad * 16;
    const char* g0 = (i0 >= 0) ? abase + (((size_t)(unsigned)i0) << 7) : zaddr;
    const char* gs = abase + (((size_t)(unsigned)(t * 16 + l15)) << 7);
    const char* g2 = (i2 >= 0) ? abase + (((size_t)(unsigned)i2) << 7) : zaddr;
    A[0] = *reinterpret_cast<const uint4v*>(g0 + qo);
    A[1] = *reinterpret_cast<const uint4v*>(g0 + qo + 64);
    A[2] = *reinterpret_cast<const uint4v*>(gs + qo);
    A[3] = *reinterpret_cast<const uint4v*>(gs + qo + 64);
    A[4] = *reinterpret_cast<const uint4v*>(g2 + qo);
    A[5] = *reinterpret_cast<const uint4v*>(g2 + qo + 64);
}

// MFMA over the 6 K-half fragments + stats + transpose-store of one tile.
template<bool DO_STATS>
__device__ __forceinline__ void conv_tile(
    const uint4v (&A)[6], const unsigned short* __restrict__ Bld,
    unsigned short* __restrict__ tl, unsigned short* __restrict__ Hout,
    int t, int lane, int l15, int quad,
    float (&lsum)[4], float (&lsq)[4])
{
    float4v acc[4] = {};
#pragma unroll
    for (int s = 0; s < 6; ++s) {
        bf16x8 a = __builtin_bit_cast(bf16x8, A[s]);
#pragma unroll
        for (int nt = 0; nt < 4; ++nt) {
            uint4v ub = *reinterpret_cast<const uint4v*>(
                Bld + (((s * 4 + nt) * 64 + lane) << 3));
            bf16x8 b = __builtin_bit_cast(bf16x8, ub);
            acc[nt] = __builtin_amdgcn_mfma_f32_16x16x32_bf16(a, b, acc[nt], 0, 0, 0);
        }
    }
    if (DO_STATS) {
#pragma unroll
        for (int nt = 0; nt < 4; ++nt) {
            lsum[nt] += acc[nt][0] + acc[nt][1] + acc[nt][2] + acc[nt][3];
            lsq[nt]  += acc[nt][0] * acc[nt][0] + acc[nt][1] * acc[nt][1]
                      + acc[nt][2] * acc[nt][2] + acc[nt][3] * acc[nt][3];
        }
    }
    // C layout: col = nt*16 + l15, row = quad*4 + reg. Transpose via per-wave
    // LDS region; global stores = coalesced 16B chunks.
#pragma unroll
    for (int nt = 0; nt < 4; ++nt)
#pragma unroll
        for (int r = 0; r < 4; ++r)
            tl[(quad * 4 + r) * 72 + nt * 16 + l15] = f2bf_bits(acc[nt][r]);
    __asm__ volatile("s_waitcnt lgkmcnt(0)" ::: "memory");
    unsigned short* op = Hout + ((size_t)t << 10);
#pragma unroll
    for (int c = 0; c < 2; ++c) {
        int chunk = c * 64 + lane;
        int r = chunk >> 3;
        int off = (chunk & 7) * 8;
        uint4v v = *reinterpret_cast<const uint4v*>(&tl[r * 72 + off]);
        *reinterpret_cast<uint4v*>(op + (r << 6) + off) = v;
    }
    __asm__ volatile("s_waitcnt lgkmcnt(0)" ::: "memory");
}

// One conv layer: out[n,d] = sum_{tap,c} A[nbr[n,tap], c] * W[tap,c,d]
// A bf16 [N,64] (row = 128 B). Wave handles 16 rows x 64 cols per tile.
template<bool DO_STATS>
__global__ __launch_bounds__(256, 4)
void conv_kernel(const unsigned short* __restrict__ Ain,
                 const float* __restrict__ Wg,
                 const int* __restrict__ nbr,
                 unsigned short* __restrict__ Hout,
                 const unsigned short* __restrict__ Zrow,
                 float* __restrict__ stats, int ntiles)
{
    __shared__ unsigned short Bld[24 * 64 * 8];    // 24 KB B-frags, lane-linear
    __shared__ unsigned short Tld[4][16 * 72];     // 9 KB store-transpose
    __shared__ float ssum[64], ssq[64];

    const int tid = threadIdx.x;
    // Stage W as bf16 MFMA B-fragments, identity-by-lane layout:
    // frag(s,nt) lane ln reg j = W[tap][(s&1)*32 + (ln>>4)*8 + j][nt*16 + (ln&15)]
    // stored at Bld[((s*4+nt)*64 + ln)*8 + j]  (coalesced source reads).
    for (int i = tid; i < 192 * 64; i += 256) {
        int kc = i >> 6, d = i & 63;               // kc = tap*64 + c
        int tap = kc >> 6, c = kc & 63;
        int s  = tap * 2 + (c >> 5);
        int qd = (c >> 3) & 3, j = c & 7;
        int ln = qd * 16 + (d & 15);
        Bld[(((s * 4 + (d >> 4)) * 64 + ln) << 3) + j] = f2bf_bits(Wg[i]);
    }
    if (DO_STATS && tid < 64) { ssum[tid] = 0.f; ssq[tid] = 0.f; }
    __syncthreads();

    const int lane = tid & 63;
    const int wid  = tid >> 6;
    const int l15  = lane & 15;
    const int quad = lane >> 4;
    const char* abase = (const char*)Ain;
    const char* zaddr = (const char*)Zrow;
    unsigned short* tl = Tld[wid];

    float lsum[4] = {0.f, 0.f, 0.f, 0.f};
    float lsq[4]  = {0.f, 0.f, 0.f, 0.f};

    const int S = gridDim.x * 4;
    int t = blockIdx.x * 4 + wid;
    if (t < ntiles) {
        size_t nb = (size_t)(t * 16 + l15) * 3;
        int iA0 = nbr[nb], iA2 = nbr[nb + 2];
        int iB0 = 0, iB2 = 0;
        uint4v Aa[6], Ab[6];
        issue_tile(Aa, abase, zaddr, iA0, iA2, t, l15, quad);
        int tn = t + S;
        if (tn < ntiles) {
            size_t nb1 = (size_t)(tn * 16 + l15) * 3;
            iA0 = nbr[nb1]; iA2 = nbr[nb1 + 2];
        }
        while (true) {
            // ---- phase A: consume Aa(t); issue Ab(tn); prefetch idx(t2) ----
            int t2 = tn + S;
            if (t2 < ntiles) {
                size_t nb2 = (size_t)(t2 * 16 + l15) * 3;
                iB0 = nbr[nb2]; iB2 = nbr[nb2 + 2];
            }
            if (tn < ntiles)
                issue_tile(Ab, abase, zaddr, iA0, iA2, tn, l15, quad);
            conv_tile<DO_STATS>(Aa, Bld, tl, Hout, t, lane, l15, quad, lsum, lsq);
            t = tn; tn = t2;
            if (t >= ntiles) break;

            // ---- phase B: consume Ab(t); issue Aa(tn); prefetch idx(t2) ----
            t2 = tn + S;
            if (t2 < ntiles) {
                size_t nb2 = (size_t)(t2 * 16 + l15) * 3;
                iA0 = nbr[nb2]; iA2 = nbr[nb2 + 2];
            }
            if (tn < ntiles)
                issue_tile(Aa, abase, zaddr, iB0, iB2, tn, l15, quad);
            conv_tile<DO_STATS>(Ab, Bld, tl, Hout, t, lane, l15, quad, lsum, lsq);
            t = tn; tn = t2;
            if (t >= ntiles) break;
        }
    }

    if (DO_STATS) {
#pragma unroll
        for (int nt = 0; nt < 4; ++nt) {
            atomicAdd(&ssum[nt * 16 + l15], lsum[nt]);
            atomicAdd(&ssq[nt * 16 + l15], lsq[nt]);
        }
        __syncthreads();
        if (tid < 64)               atomicAdd(&stats[tid], ssum[tid]);
        else if (tid < 128)         atomicAdd(&stats[tid], ssq[tid - 64]);
    }
}

__global__ __launch_bounds__(256)
void bn_relu_kernel(const unsigned short* __restrict__ H,
                    const float* __restrict__ stats,
                    const float* __restrict__ gamma,
                    const float* __restrict__ beta,
                    float* __restrict__ out, size_t ntot, float invN)
{
    __shared__ float sscale[64], sbias[64];
    const int tid = threadIdx.x;
    if (tid < 64) {
        float mean = stats[tid] * invN;
        float var  = stats[tid + 64] * invN - mean * mean;
        float sc   = gamma[tid] * rsqrtf(var + 1e-5f);
        sscale[tid] = sc;
        sbias[tid]  = beta[tid] - mean * sc;
    }
    __syncthreads();
    size_t i0 = ((size_t)blockIdx.x * 256 + tid) * 8;
    const size_t stride = (size_t)gridDim.x * 2048;   // multiple of 64
    const int cb = (int)(i0 & 63);
    float sc[8], bs[8];
#pragma unroll
    for (int j = 0; j < 8; ++j) { sc[j] = sscale[cb + j]; bs[j] = sbias[cb + j]; }
    for (size_t i = i0; i < ntot; i += stride) {
        uint4v v = *reinterpret_cast<const uint4v*>(H + i);
        float4v o0, o1;
#pragma unroll
        for (int j = 0; j < 4; ++j) {
            float lo = bf2f((unsigned short)(v[j] & 0xffffu));
            float hi = bf2f((unsigned short)(v[j] >> 16));
            float r0 = fmaxf(lo * sc[2 * j]     + bs[2 * j],     0.f);
            float r1 = fmaxf(hi * sc[2 * j + 1] + bs[2 * j + 1], 0.f);
            if (j < 2) { o0[2 * j] = r0; o0[2 * j + 1] = r1; }
            else       { o1[2 * (j - 2)] = r0; o1[2 * (j - 2) + 1] = r1; }
        }
        *reinterpret_cast<float4v*>(out + i)     = o0;
        *reinterpret_cast<float4v*>(out + i + 4) = o1;
    }
}

extern "C" void kernel_launch(void* const* d_in, const int* in_sizes, int n_in,
                              void* d_out, int out_size, void* d_ws, size_t ws_size,
                              hipStream_t stream)
{
    const float* feats = (const float*)d_in[0];
    const float* W1    = (const float*)d_in[1];
    const float* W2    = (const float*)d_in[2];
    const float* W3    = (const float*)d_in[3];
    const float* gamma = (const float*)d_in[4];
    const float* beta  = (const float*)d_in[5];
    const int* nbr_z   = (const int*)d_in[6];
    const int* nbr_y   = (const int*)d_in[7];
    const int* nbr_x   = (const int*)d_in[8];

    const int N = in_sizes[0] / 64;      // 1,000,000
    const int ntiles = N / 16;

    // ws layout: [stats 512B][zero-row 512B][feats-bf16 128MB][h1][h2]; h3
    // reuses the feats-bf16 buffer (dead after conv1).
    char* ws = (char*)d_ws;
    float* stats = (float*)ws;
    unsigned short* zrow = (unsigned short*)(ws + 512);
    unsigned short* a0 = (unsigned short*)(ws + 1024);
    unsigned short* h1 = a0 + (size_t)N * 64;
    unsigned short* h2 = h1 + (size_t)N * 64;
    unsigned short* h3 = a0;

    hipMemsetAsync(ws, 0, 1024, stream);  // stats + zero-row (re-poisoned ws)

    dim3 blk(256);
    cvt_kernel<<<dim3(4096), blk, 0, stream>>>(feats, a0, (size_t)N * 8);
    conv_kernel<false><<<dim3(1024), blk, 0, stream>>>(a0, W1, nbr_z, h1, zrow, nullptr, ntiles);
    conv_kernel<false><<<dim3(1024), blk, 0, stream>>>(h1, W2, nbr_y, h2, zrow, nullptr, ntiles);
    conv_kernel<true ><<<dim3(1024), blk, 0, stream>>>(h2, W3, nbr_x, h3, zrow, stats, ntiles);
    bn_relu_kernel<<<dim3(8192), blk, 0, stream>>>(h3, stats, gamma, beta,
                                                   (float*)d_out, (size_t)N * 64,
                                                   1.0f / (float)N);
}

// Round 2
// 677.341 us; speedup vs baseline: 1.1162x; 1.0466x over previous
//
#include <hip/hip_runtime.h>
#include <cstdint>
#include <cstddef>

// SparseConv3d: 3 chained sparse 3-tap convs (C=64) + BatchNorm(train) + ReLU.
// R4: (a) cvt pass deleted -- conv1 gathers fp32 feats directly and packs to
// bf16 in registers (gather taps are ~93% zero-row anyway, so the fp32 row
// width costs almost nothing); (b) wave-uniform tap-skip: per tile+tap, if no
// row has a real neighbor (P ~= 0.93^16 ~= 31%) skip that tap's 8 ds_read_b128
// + 8 MFMAs entirely (adds exact zeros -> bit-identical). Loads stay
// unconditional so compiler vmcnt tracking keeps the tile-ahead pipeline.

typedef __attribute__((ext_vector_type(4))) float float4v;
typedef __attribute__((ext_vector_type(4))) unsigned int uint4v;
typedef __attribute__((ext_vector_type(8))) __bf16 bf16x8;
typedef __attribute__((ext_vector_type(8))) unsigned short ushort8;

__device__ __forceinline__ unsigned short f2bf_bits(float f) {
    unsigned int u = __builtin_bit_cast(unsigned int, f);
    u += 0x7fffu + ((u >> 16) & 1u);   // round-to-nearest-even (finite inputs)
    return (unsigned short)(u >> 16);
}
__device__ __forceinline__ float bf2f(unsigned short b) {
    unsigned int u = ((unsigned int)b) << 16;
    return __builtin_bit_cast(float, u);
}

// Stage W as bf16 MFMA B-fragments, identity-by-lane layout:
// frag(s,nt) lane ln reg j = W[tap][(s&1)*32 + (ln>>4)*8 + j][nt*16 + (ln&15)]
__device__ __forceinline__ void stage_W(const float* __restrict__ Wg,
                                        unsigned short* __restrict__ Bld, int tid)
{
    for (int i = tid; i < 192 * 64; i += 256) {
        int kc = i >> 6, d = i & 63;               // kc = tap*64 + c
        int tap = kc >> 6, c = kc & 63;
        int s  = tap * 2 + (c >> 5);
        int qd = (c >> 3) & 3, j = c & 7;
        int ln = qd * 16 + (d & 15);
        Bld[(((s * 4 + (d >> 4)) * 64 + ln) << 3) + j] = f2bf_bits(Wg[i]);
    }
}

// One tap's 8 MFMAs with lane-linear (conflict-free) B-frag reads from LDS.
__device__ __forceinline__ void mfma_tap(const unsigned short* __restrict__ Bld,
                                         int lane, bf16x8 a0, bf16x8 a1, int s0,
                                         float4v (&acc)[4])
{
#pragma unroll
    for (int nt = 0; nt < 4; ++nt) {
        uint4v ub = *reinterpret_cast<const uint4v*>(
            Bld + (((s0 * 4 + nt) * 64 + lane) << 3));
        acc[nt] = __builtin_amdgcn_mfma_f32_16x16x32_bf16(
            a0, __builtin_bit_cast(bf16x8, ub), acc[nt], 0, 0, 0);
    }
#pragma unroll
    for (int nt = 0; nt < 4; ++nt) {
        uint4v ub = *reinterpret_cast<const uint4v*>(
            Bld + ((((s0 + 1) * 4 + nt) * 64 + lane) << 3));
        acc[nt] = __builtin_amdgcn_mfma_f32_16x16x32_bf16(
            a1, __builtin_bit_cast(bf16x8, ub), acc[nt], 0, 0, 0);
    }
}

// stats + transpose-store of one tile. C layout: col = nt*16+l15, row = quad*4+r.
template<bool DO_STATS>
__device__ __forceinline__ void tile_epilogue(const float4v (&acc)[4],
    unsigned short* __restrict__ tl, unsigned short* __restrict__ Hout,
    int t, int lane, int l15, int quad, float (&lsum)[4], float (&lsq)[4])
{
    if (DO_STATS) {
#pragma unroll
        for (int nt = 0; nt < 4; ++nt) {
            lsum[nt] += acc[nt][0] + acc[nt][1] + acc[nt][2] + acc[nt][3];
            lsq[nt]  += acc[nt][0] * acc[nt][0] + acc[nt][1] * acc[nt][1]
                      + acc[nt][2] * acc[nt][2] + acc[nt][3] * acc[nt][3];
        }
    }
#pragma unroll
    for (int nt = 0; nt < 4; ++nt)
#pragma unroll
        for (int r = 0; r < 4; ++r)
            tl[(quad * 4 + r) * 72 + nt * 16 + l15] = f2bf_bits(acc[nt][r]);
    __asm__ volatile("s_waitcnt lgkmcnt(0)" ::: "memory");
    unsigned short* op = Hout + ((size_t)t << 10);
#pragma unroll
    for (int c = 0; c < 2; ++c) {
        int chunk = c * 64 + lane;
        int r = chunk >> 3;
        int off = (chunk & 7) * 8;
        uint4v v = *reinterpret_cast<const uint4v*>(&tl[r * 72 + off]);
        *reinterpret_cast<uint4v*>(op + (r << 6) + off) = v;
    }
    __asm__ volatile("s_waitcnt lgkmcnt(0)" ::: "memory");
}

// ---------------- bf16-input conv (layers 2,3) ----------------

__device__ __forceinline__ void issue_bf16(
    uint4v (&A)[6], const char* __restrict__ abase,
    const char* __restrict__ zaddr, int i0, int i2, int t, int l15, int quad)
{
    const int qo = quad * 16;
    const char* g0 = (i0 >= 0) ? abase + (((size_t)(unsigned)i0) << 7) : zaddr;
    const char* gs = abase + (((size_t)(unsigned)(t * 16 + l15)) << 7);
    const char* g2 = (i2 >= 0) ? abase + (((size_t)(unsigned)i2) << 7) : zaddr;
    A[0] = *reinterpret_cast<const uint4v*>(g0 + qo);
    A[1] = *reinterpret_cast<const uint4v*>(g0 + qo + 64);
    A[2] = *reinterpret_cast<const uint4v*>(gs + qo);
    A[3] = *reinterpret_cast<const uint4v*>(gs + qo + 64);
    A[4] = *reinterpret_cast<const uint4v*>(g2 + qo);
    A[5] = *reinterpret_cast<const uint4v*>(g2 + qo + 64);
}

template<bool DO_STATS>
__device__ __forceinline__ void consume_bf16(
    const uint4v (&A)[6], int fl, const unsigned short* __restrict__ Bld,
    unsigned short* __restrict__ tl, unsigned short* __restrict__ Hout,
    int t, int lane, int l15, int quad, float (&lsum)[4], float (&lsq)[4])
{
    float4v acc[4] = {};
    if (fl & 1)
        mfma_tap(Bld, lane, __builtin_bit_cast(bf16x8, A[0]),
                 __builtin_bit_cast(bf16x8, A[1]), 0, acc);
    mfma_tap(Bld, lane, __builtin_bit_cast(bf16x8, A[2]),
             __builtin_bit_cast(bf16x8, A[3]), 2, acc);
    if (fl & 2)
        mfma_tap(Bld, lane, __builtin_bit_cast(bf16x8, A[4]),
                 __builtin_bit_cast(bf16x8, A[5]), 4, acc);
    tile_epilogue<DO_STATS>(acc, tl, Hout, t, lane, l15, quad, lsum, lsq);
}

template<bool DO_STATS>
__global__ __launch_bounds__(256, 4)
void conv_kernel(const unsigned short* __restrict__ Ain,
                 const float* __restrict__ Wg,
                 const int* __restrict__ nbr,
                 unsigned short* __restrict__ Hout,
                 const unsigned short* __restrict__ Zrow,
                 float* __restrict__ stats, int ntiles)
{
    __shared__ unsigned short Bld[24 * 64 * 8];    // 24 KB B-frags, lane-linear
    __shared__ unsigned short Tld[4][16 * 72];     // 9 KB store-transpose
    __shared__ float ssum[64], ssq[64];

    const int tid = threadIdx.x;
    stage_W(Wg, Bld, tid);
    if (DO_STATS && tid < 64) { ssum[tid] = 0.f; ssq[tid] = 0.f; }
    __syncthreads();

    const int lane = tid & 63;
    const int wid  = tid >> 6;
    const int l15  = lane & 15;
    const int quad = lane >> 4;
    const char* abase = (const char*)Ain;
    const char* zaddr = (const char*)Zrow;
    unsigned short* tl = Tld[wid];

    float lsum[4] = {0.f, 0.f, 0.f, 0.f};
    float lsq[4]  = {0.f, 0.f, 0.f, 0.f};

    const int S = gridDim.x * 4;
    int t = blockIdx.x * 4 + wid;
    if (t < ntiles) {
        uint4v Aa[6], Ab[6];
        int flA = 0, flB = 0;
        int iN0 = 0, iN2 = 0;
        {
            size_t nb = (size_t)(t * 16 + l15) * 3;
            int i0 = nbr[nb], i2 = nbr[nb + 2];
            flA = (__any(i0 >= 0) ? 1 : 0) | (__any(i2 >= 0) ? 2 : 0);
            issue_bf16(Aa, abase, zaddr, i0, i2, t, l15, quad);
        }
        int tn = t + S;
        if (tn < ntiles) {
            size_t nb = (size_t)(tn * 16 + l15) * 3;
            iN0 = nbr[nb]; iN2 = nbr[nb + 2];
        }
        while (true) {
            int t2 = tn + S;
            if (tn < ntiles) {
                flB = (__any(iN0 >= 0) ? 1 : 0) | (__any(iN2 >= 0) ? 2 : 0);
                issue_bf16(Ab, abase, zaddr, iN0, iN2, tn, l15, quad);
            }
            if (t2 < ntiles) {
                size_t nb = (size_t)(t2 * 16 + l15) * 3;
                iN0 = nbr[nb]; iN2 = nbr[nb + 2];
            }
            consume_bf16<DO_STATS>(Aa, flA, Bld, tl, Hout, t, lane, l15, quad, lsum, lsq);
            t = tn; tn = t2;
            if (t >= ntiles) break;

            t2 = tn + S;
            if (tn < ntiles) {
                flA = (__any(iN0 >= 0) ? 1 : 0) | (__any(iN2 >= 0) ? 2 : 0);
                issue_bf16(Aa, abase, zaddr, iN0, iN2, tn, l15, quad);
            }
            if (t2 < ntiles) {
                size_t nb = (size_t)(t2 * 16 + l15) * 3;
                iN0 = nbr[nb]; iN2 = nbr[nb + 2];
            }
            consume_bf16<DO_STATS>(Ab, flB, Bld, tl, Hout, t, lane, l15, quad, lsum, lsq);
            t = tn; tn = t2;
            if (t >= ntiles) break;
        }
    }

    if (DO_STATS) {
#pragma unroll
        for (int nt = 0; nt < 4; ++nt) {
            atomicAdd(&ssum[nt * 16 + l15], lsum[nt]);
            atomicAdd(&ssq[nt * 16 + l15], lsq[nt]);
        }
        __syncthreads();
        if (tid < 64)               atomicAdd(&stats[tid], ssum[tid]);
        else if (tid < 128)         atomicAdd(&stats[tid], ssq[tid - 64]);
    }
}

// ---------------- fp32-input conv (layer 1; cvt pass fused away) ----------------

__device__ __forceinline__ void issue_f32(
    uint4v (&R)[12], const char* __restrict__ fbase,
    const char* __restrict__ zaddr, int i0, int i2, int t, int l15, int quad)
{
    const int qo = quad * 32;
    const char* g0 = (i0 >= 0) ? fbase + ((size_t)(unsigned)i0) * 256 : zaddr;
    const char* gs = fbase + ((size_t)(unsigned)(t * 16 + l15)) * 256;
    const char* g2 = (i2 >= 0) ? fbase + ((size_t)(unsigned)i2) * 256 : zaddr;
    R[0]  = *reinterpret_cast<const uint4v*>(g0 + qo);
    R[1]  = *reinterpret_cast<const uint4v*>(g0 + qo + 16);
    R[2]  = *reinterpret_cast<const uint4v*>(g0 + qo + 128);
    R[3]  = *reinterpret_cast<const uint4v*>(g0 + qo + 144);
    R[4]  = *reinterpret_cast<const uint4v*>(gs + qo);
    R[5]  = *reinterpret_cast<const uint4v*>(gs + qo + 16);
    R[6]  = *reinterpret_cast<const uint4v*>(gs + qo + 128);
    R[7]  = *reinterpret_cast<const uint4v*>(gs + qo + 144);
    R[8]  = *reinterpret_cast<const uint4v*>(g2 + qo);
    R[9]  = *reinterpret_cast<const uint4v*>(g2 + qo + 16);
    R[10] = *reinterpret_cast<const uint4v*>(g2 + qo + 128);
    R[11] = *reinterpret_cast<const uint4v*>(g2 + qo + 144);
}

__device__ __forceinline__ bf16x8 pack_frag(uint4v lo, uint4v hi)
{
    float4v f0 = __builtin_bit_cast(float4v, lo);
    float4v f1 = __builtin_bit_cast(float4v, hi);
    ushort8 u;
#pragma unroll
    for (int j = 0; j < 4; ++j) {
        u[j]     = f2bf_bits(f0[j]);
        u[j + 4] = f2bf_bits(f1[j]);
    }
    return __builtin_bit_cast(bf16x8, u);
}

__device__ __forceinline__ void consume_f32(
    const uint4v (&R)[12], int fl, const unsigned short* __restrict__ Bld,
    unsigned short* __restrict__ tl, unsigned short* __restrict__ Hout,
    int t, int lane, int l15, int quad, float (&lsum)[4], float (&lsq)[4])
{
    float4v acc[4] = {};
    if (fl & 1)
        mfma_tap(Bld, lane, pack_frag(R[0], R[1]), pack_frag(R[2], R[3]), 0, acc);
    mfma_tap(Bld, lane, pack_frag(R[4], R[5]), pack_frag(R[6], R[7]), 2, acc);
    if (fl & 2)
        mfma_tap(Bld, lane, pack_frag(R[8], R[9]), pack_frag(R[10], R[11]), 4, acc);
    tile_epilogue<false>(acc, tl, Hout, t, lane, l15, quad, lsum, lsq);
}

__global__ __launch_bounds__(256, 3)
void conv1_kernel(const float* __restrict__ Fin,
                  const float* __restrict__ Wg,
                  const int* __restrict__ nbr,
                  unsigned short* __restrict__ Hout,
                  const float* __restrict__ Zrowf, int ntiles)
{
    __shared__ unsigned short Bld[24 * 64 * 8];
    __shared__ unsigned short Tld[4][16 * 72];

    const int tid = threadIdx.x;
    stage_W(Wg, Bld, tid);
    __syncthreads();

    const int lane = tid & 63;
    const int wid  = tid >> 6;
    const int l15  = lane & 15;
    const int quad = lane >> 4;
    const char* fbase = (const char*)Fin;
    const char* zaddr = (const char*)Zrowf;
    unsigned short* tl = Tld[wid];

    float lsum[4] = {0.f, 0.f, 0.f, 0.f};
    float lsq[4]  = {0.f, 0.f, 0.f, 0.f};

    const int S = gridDim.x * 4;
    int t = blockIdx.x * 4 + wid;
    if (t < ntiles) {
        uint4v Ra[12], Rb[12];
        int flA = 0, flB = 0;
        int iN0 = 0, iN2 = 0;
        {
            size_t nb = (size_t)(t * 16 + l15) * 3;
            int i0 = nbr[nb], i2 = nbr[nb + 2];
            flA = (__any(i0 >= 0) ? 1 : 0) | (__any(i2 >= 0) ? 2 : 0);
            issue_f32(Ra, fbase, zaddr, i0, i2, t, l15, quad);
        }
        int tn = t + S;
        if (tn < ntiles) {
            size_t nb = (size_t)(tn * 16 + l15) * 3;
            iN0 = nbr[nb]; iN2 = nbr[nb + 2];
        }
        while (true) {
            int t2 = tn + S;
            if (tn < ntiles) {
                flB = (__any(iN0 >= 0) ? 1 : 0) | (__any(iN2 >= 0) ? 2 : 0);
                issue_f32(Rb, fbase, zaddr, iN0, iN2, tn, l15, quad);
            }
            if (t2 < ntiles) {
                size_t nb = (size_t)(t2 * 16 + l15) * 3;
                iN0 = nbr[nb]; iN2 = nbr[nb + 2];
            }
            consume_f32(Ra, flA, Bld, tl, Hout, t, lane, l15, quad, lsum, lsq);
            t = tn; tn = t2;
            if (t >= ntiles) break;

            t2 = tn + S;
            if (tn < ntiles) {
                flA = (__any(iN0 >= 0) ? 1 : 0) | (__any(iN2 >= 0) ? 2 : 0);
                issue_f32(Ra, fbase, zaddr, iN0, iN2, tn, l15, quad);
            }
            if (t2 < ntiles) {
                size_t nb = (size_t)(t2 * 16 + l15) * 3;
                iN0 = nbr[nb]; iN2 = nbr[nb + 2];
            }
            consume_f32(Rb, flB, Bld, tl, Hout, t, lane, l15, quad, lsum, lsq);
            t = tn; tn = t2;
            if (t >= ntiles) break;
        }
    }
}

// ---------------- BatchNorm(train) + ReLU ----------------

__global__ __launch_bounds__(256)
void bn_relu_kernel(const unsigned short* __restrict__ H,
                    const float* __restrict__ stats,
                    const float* __restrict__ gamma,
                    const float* __restrict__ beta,
                    float* __restrict__ out, size_t ntot, float invN)
{
    __shared__ float sscale[64], sbias[64];
    const int tid = threadIdx.x;
    if (tid < 64) {
        float mean = stats[tid] * invN;
        float var  = stats[tid + 64] * invN - mean * mean;
        float sc   = gamma[tid] * rsqrtf(var + 1e-5f);
        sscale[tid] = sc;
        sbias[tid]  = beta[tid] - mean * sc;
    }
    __syncthreads();
    size_t i0 = ((size_t)blockIdx.x * 256 + tid) * 8;
    const size_t stride = (size_t)gridDim.x * 2048;   // multiple of 64
    const int cb = (int)(i0 & 63);
    float sc[8], bs[8];
#pragma unroll
    for (int j = 0; j < 8; ++j) { sc[j] = sscale[cb + j]; bs[j] = sbias[cb + j]; }
    for (size_t i = i0; i < ntot; i += stride) {
        uint4v v = *reinterpret_cast<const uint4v*>(H + i);
        float4v o0, o1;
#pragma unroll
        for (int j = 0; j < 4; ++j) {
            float lo = bf2f((unsigned short)(v[j] & 0xffffu));
            float hi = bf2f((unsigned short)(v[j] >> 16));
            float r0 = fmaxf(lo * sc[2 * j]     + bs[2 * j],     0.f);
            float r1 = fmaxf(hi * sc[2 * j + 1] + bs[2 * j + 1], 0.f);
            if (j < 2) { o0[2 * j] = r0; o0[2 * j + 1] = r1; }
            else       { o1[2 * (j - 2)] = r0; o1[2 * (j - 2) + 1] = r1; }
        }
        *reinterpret_cast<float4v*>(out + i)     = o0;
        *reinterpret_cast<float4v*>(out + i + 4) = o1;
    }
}

extern "C" void kernel_launch(void* const* d_in, const int* in_sizes, int n_in,
                              void* d_out, int out_size, void* d_ws, size_t ws_size,
                              hipStream_t stream)
{
    const float* feats = (const float*)d_in[0];
    const float* W1    = (const float*)d_in[1];
    const float* W2    = (const float*)d_in[2];
    const float* W3    = (const float*)d_in[3];
    const float* gamma = (const float*)d_in[4];
    const float* beta  = (const float*)d_in[5];
    const int* nbr_z   = (const int*)d_in[6];
    const int* nbr_y   = (const int*)d_in[7];
    const int* nbr_x   = (const int*)d_in[8];

    const int N = in_sizes[0] / 64;      // 1,000,000
    const int ntiles = N / 16;

    // ws layout: [stats 512B][zero-row 512B (covers fp32 256B + bf16 128B)]
    //            [h1 128MB][h2 128MB][h3 128MB]
    char* ws = (char*)d_ws;
    float* stats = (float*)ws;
    float* zrowf = (float*)(ws + 512);
    unsigned short* zrow = (unsigned short*)(ws + 512);
    unsigned short* h1 = (unsigned short*)(ws + 1024);
    unsigned short* h2 = h1 + (size_t)N * 64;
    unsigned short* h3 = h2 + (size_t)N * 64;

    hipMemsetAsync(ws, 0, 1024, stream);  // stats + zero-row (re-poisoned ws)

    dim3 blk(256);
    conv1_kernel<<<dim3(1024), blk, 0, stream>>>(feats, W1, nbr_z, h1, zrowf, ntiles);
    conv_kernel<false><<<dim3(1024), blk, 0, stream>>>(h1, W2, nbr_y, h2, zrow, nullptr, ntiles);
    conv_kernel<true ><<<dim3(1024), blk, 0, stream>>>(h2, W3, nbr_x, h3, zrow, stats, ntiles);
    bn_relu_kernel<<<dim3(8192), blk, 0, stream>>>(h3, stats, gamma, beta,
                                                   (float*)d_out, (size_t)N * 64,
                                                   1.0f / (float)N);
}